// Round 1
// baseline (1795.841 us; speedup 1.0000x reference)
//
#include <hip/hip_runtime.h>

#define N_USERS 100000
#define N_ITEMS 50000
#define DIM     64
#define N_NODES (N_USERS + N_ITEMS + 1)   /* 150001 */
#define N_EDGES 4800000

static constexpr long long NF = (long long)N_NODES * DIM;   // 9,600,064 floats per tensor

// ---------------------------------------------------------------------------
// ego = concat(user_emb, item_emb)  (float4-vectorized; both parts %4 == 0)
// ---------------------------------------------------------------------------
__global__ void concat_kernel(const float4* __restrict__ user,
                              const float4* __restrict__ item,
                              float4* __restrict__ ego) {
    int i = blockIdx.x * blockDim.x + threadIdx.x;
    const int userF4 = N_USERS * DIM / 4;         // 1,600,000
    const int totF4  = (int)(NF / 4);             // 2,400,016
    if (i < userF4)      ego[i] = user[i];
    else if (i < totF4)  ego[i] = item[i - userF4];
}

// ---------------------------------------------------------------------------
// CSR build: histogram of rows
// ---------------------------------------------------------------------------
__global__ void hist_kernel(const int* __restrict__ rows, int* __restrict__ deg) {
    int e = blockIdx.x * blockDim.x + threadIdx.x;
    if (e < N_EDGES) atomicAdd(&deg[rows[e]], 1);
}

// ---------------------------------------------------------------------------
// Single-block thread-coarsened exclusive scan: deg[0..N_NODES) -> row_ptr,
// cursor (cursor is the scatter write-head copy). row_ptr[N_NODES] = E.
// ---------------------------------------------------------------------------
__global__ void __launch_bounds__(1024)
scan_kernel(const int* __restrict__ deg,
            int* __restrict__ row_ptr,
            int* __restrict__ cursor) {
    const int M = N_NODES;
    const int T = 1024;
    const int ITEMS = (M + T - 1) / T;            // 147
    __shared__ int sums[T];
    int t = threadIdx.x;
    int begin = t * ITEMS;
    int end   = min(begin + ITEMS, M);
    int s = 0;
    for (int i = begin; i < end; ++i) s += deg[i];
    sums[t] = s;
    __syncthreads();
    // Hillis-Steele inclusive scan over 1024 per-thread sums
    for (int off = 1; off < T; off <<= 1) {
        int v = sums[t];
        int u = (t >= off) ? sums[t - off] : 0;
        __syncthreads();
        sums[t] = v + u;
        __syncthreads();
    }
    int running = (t == 0) ? 0 : sums[t - 1];     // exclusive prefix
    for (int i = begin; i < end; ++i) {
        row_ptr[i] = running;
        cursor[i]  = running;
        running += deg[i];
    }
    if (t == T - 1) row_ptr[M] = sums[T - 1];     // total == N_EDGES
}

// ---------------------------------------------------------------------------
// Scatter edges into row-sorted order (order within a row is arbitrary — fp32
// sum order differs from ref but well within the absmax threshold)
// ---------------------------------------------------------------------------
__global__ void scatter_kernel(const int* __restrict__ rows,
                               const int* __restrict__ cols,
                               const float* __restrict__ vals,
                               int* __restrict__ cursor,
                               int* __restrict__ scol,
                               float* __restrict__ sval) {
    int e = blockIdx.x * blockDim.x + threadIdx.x;
    if (e < N_EDGES) {
        int r = rows[e];
        int p = atomicAdd(&cursor[r], 1);
        scol[p] = cols[e];
        sval[p] = vals[e];
    }
}

// ---------------------------------------------------------------------------
// CSR SpMM: one wave (64 lanes) per output row; lane d owns dim d.
// Gather h[col*64+d] is a coalesced 256B read; no atomics.
// ---------------------------------------------------------------------------
__global__ void spmm_csr_kernel(const int* __restrict__ row_ptr,
                                const int* __restrict__ scol,
                                const float* __restrict__ sval,
                                const float* __restrict__ hin,
                                float* __restrict__ hout) {
    int wave = (blockIdx.x * blockDim.x + threadIdx.x) >> 6;
    int lane = threadIdx.x & 63;
    if (wave >= N_NODES) return;
    int start = row_ptr[wave];
    int end   = row_ptr[wave + 1];
    float acc0 = 0.f, acc1 = 0.f;
    int e = start;
    for (; e + 2 <= end; e += 2) {
        int   c0 = scol[e],   c1 = scol[e + 1];
        float v0 = sval[e],   v1 = sval[e + 1];
        acc0 += v0 * hin[c0 * DIM + lane];
        acc1 += v1 * hin[c1 * DIM + lane];
    }
    if (e < end)
        acc0 += sval[e] * hin[scol[e] * DIM + lane];
    hout[wave * DIM + lane] = acc0 + acc1;
}

// ---------------------------------------------------------------------------
// Fallback SpMM via fp32 atomics (used only if ws_size too small for CSR)
// 4 edges per 256-thread block; lane d of each wave owns dim d.
// ---------------------------------------------------------------------------
__global__ void spmm_atomic_kernel(const int* __restrict__ rows,
                                   const int* __restrict__ cols,
                                   const float* __restrict__ vals,
                                   const float* __restrict__ hin,
                                   float* __restrict__ hout) {
    int e = blockIdx.x * 4 + (threadIdx.x >> 6);
    int d = threadIdx.x & 63;
    if (e < N_EDGES) {
        int c = cols[e];
        int r = rows[e];
        float v = vals[e];
        atomicAdd(&hout[r * DIM + d], v * hin[c * DIM + d]);
    }
}

// ---------------------------------------------------------------------------
// h_sum = ego + h1 + h2 + h3
// ---------------------------------------------------------------------------
__global__ void sum_kernel(const float4* __restrict__ a,
                           const float4* __restrict__ b,
                           const float4* __restrict__ c,
                           const float4* __restrict__ d,
                           float4* __restrict__ out) {
    int i = blockIdx.x * blockDim.x + threadIdx.x;
    if (i < (int)(NF / 4)) {
        float4 x = a[i], y = b[i], z = c[i], w = d[i];
        out[i] = make_float4(x.x + y.x + z.x + w.x,
                             x.y + y.y + z.y + w.y,
                             x.z + y.z + z.z + w.z,
                             x.w + y.w + z.w + w.w);
    }
}

extern "C" void kernel_launch(void* const* d_in, const int* in_sizes, int n_in,
                              void* d_out, int out_size, void* d_ws, size_t ws_size,
                              hipStream_t stream) {
    const float* user = (const float*)d_in[0];
    const float* item = (const float*)d_in[1];
    const float* vals = (const float*)d_in[2];
    const int*   rows = (const int*)d_in[3];
    const int*   cols = (const int*)d_in[4];

    float* out  = (float*)d_out;
    float* hsum = out;
    float* ego  = out + NF;
    float* h1   = out + 2 * NF;
    float* h2   = out + 3 * NF;
    float* h3   = out + 4 * NF;

    const int totF4 = (int)(NF / 4);

    // ego = concat(user, item) directly into its output slice
    concat_kernel<<<(totF4 + 255) / 256, 256, 0, stream>>>(
        (const float4*)user, (const float4*)item, (float4*)ego);

    // workspace layout for CSR path
    const size_t nPtr = (size_t)(N_NODES + 2);             // padded
    size_t need = (3 * nPtr + 2 * (size_t)N_EDGES) * 4;    // ~40.2 MB

    if (ws_size >= need) {
        int*   deg     = (int*)d_ws;
        int*   row_ptr = deg + nPtr;
        int*   cursor  = row_ptr + nPtr;
        int*   scol    = cursor + nPtr;
        float* sval    = (float*)(scol + N_EDGES);

        hipMemsetAsync(deg, 0, (size_t)N_NODES * sizeof(int), stream);
        hist_kernel<<<(N_EDGES + 255) / 256, 256, 0, stream>>>(rows, deg);
        scan_kernel<<<1, 1024, 0, stream>>>(deg, row_ptr, cursor);
        scatter_kernel<<<(N_EDGES + 255) / 256, 256, 0, stream>>>(
            rows, cols, vals, cursor, scol, sval);

        const int spmmBlocks = (N_NODES * 64 + 255) / 256;  // 1 wave per row
        spmm_csr_kernel<<<spmmBlocks, 256, 0, stream>>>(row_ptr, scol, sval, ego, h1);
        spmm_csr_kernel<<<spmmBlocks, 256, 0, stream>>>(row_ptr, scol, sval, h1,  h2);
        spmm_csr_kernel<<<spmmBlocks, 256, 0, stream>>>(row_ptr, scol, sval, h2,  h3);
    } else {
        // fallback: atomic SpMM straight into output slices (h1..h3 contiguous)
        hipMemsetAsync(h1, 0, (size_t)(3 * NF) * sizeof(float), stream);
        const int ablocks = (N_EDGES + 3) / 4;
        spmm_atomic_kernel<<<ablocks, 256, 0, stream>>>(rows, cols, vals, ego, h1);
        spmm_atomic_kernel<<<ablocks, 256, 0, stream>>>(rows, cols, vals, h1,  h2);
        spmm_atomic_kernel<<<ablocks, 256, 0, stream>>>(rows, cols, vals, h2,  h3);
    }

    sum_kernel<<<(totF4 + 255) / 256, 256, 0, stream>>>(
        (const float4*)ego, (const float4*)h1, (const float4*)h2, (const float4*)h3,
        (float4*)hsum);
}

// Round 2
// 1327.755 us; speedup vs baseline: 1.3525x; 1.3525x over previous
//
#include <hip/hip_runtime.h>

#define N_USERS 100000
#define N_ITEMS 50000
#define DIM     64
#define N_NODES (N_USERS + N_ITEMS + 1)   /* 150001 */
#define N_EDGES 4800000

static constexpr long long NF = (long long)N_NODES * DIM;   // 9,600,064 floats per tensor

// ------------------- scan geometry -------------------
#define SCAN_T      256
#define SCAN_ITEMS  8
#define SCAN_CHUNK  (SCAN_T * SCAN_ITEMS)                    /* 2048 */
#define SCAN_NBLK   ((N_NODES + SCAN_CHUNK - 1) / SCAN_CHUNK) /* 74 */

// ---------------------------------------------------------------------------
// ego = concat(user_emb, item_emb)  (float4-vectorized)
// ---------------------------------------------------------------------------
__global__ void concat_kernel(const float4* __restrict__ user,
                              const float4* __restrict__ item,
                              float4* __restrict__ ego) {
    int i = blockIdx.x * blockDim.x + threadIdx.x;
    const int userF4 = N_USERS * DIM / 4;
    const int totF4  = (int)(NF / 4);
    if (i < userF4)      ego[i] = user[i];
    else if (i < totF4)  ego[i] = item[i - userF4];
}

// ---------------------------------------------------------------------------
// CSR build step 1: histogram of rows
// ---------------------------------------------------------------------------
__global__ void hist_kernel(const int* __restrict__ rows, int* __restrict__ deg) {
    int e = blockIdx.x * blockDim.x + threadIdx.x;
    if (e < N_EDGES) atomicAdd(&deg[rows[e]], 1);
}

// ---------------------------------------------------------------------------
// CSR build step 2a: per-block partial sums of deg (74 blocks x 2048 elems)
// ---------------------------------------------------------------------------
__global__ void __launch_bounds__(SCAN_T)
scan_a_kernel(const int* __restrict__ deg, int* __restrict__ bsum) {
    __shared__ int lds[SCAN_T];
    int b = blockIdx.x, t = threadIdx.x;
    int base = b * SCAN_CHUNK + t * SCAN_ITEMS;
    int s = 0;
    #pragma unroll
    for (int i = 0; i < SCAN_ITEMS; ++i) {
        int idx = base + i;
        s += (idx < N_NODES) ? deg[idx] : 0;
    }
    lds[t] = s;
    __syncthreads();
    for (int off = SCAN_T / 2; off > 0; off >>= 1) {
        if (t < off) lds[t] += lds[t + off];
        __syncthreads();
    }
    if (t == 0) bsum[b] = lds[0];
}

// ---------------------------------------------------------------------------
// CSR build step 2b: exclusive scan of the 74 block sums (one tiny block)
// ---------------------------------------------------------------------------
__global__ void __launch_bounds__(128)
scan_b_kernel(const int* __restrict__ bsum, int* __restrict__ boff) {
    __shared__ int lds[128];
    int t = threadIdx.x;
    lds[t] = (t < SCAN_NBLK) ? bsum[t] : 0;
    __syncthreads();
    for (int off = 1; off < 128; off <<= 1) {
        int x = lds[t];
        int y = (t >= off) ? lds[t - off] : 0;
        __syncthreads();
        lds[t] = x + y;
        __syncthreads();
    }
    if (t < SCAN_NBLK) boff[t] = (t == 0) ? 0 : lds[t - 1];
}

// ---------------------------------------------------------------------------
// CSR build step 2c: block-local exclusive scan + block offset -> row_ptr,cursor
// ---------------------------------------------------------------------------
__global__ void __launch_bounds__(SCAN_T)
scan_c_kernel(const int* __restrict__ deg, const int* __restrict__ boff,
              int* __restrict__ row_ptr, int* __restrict__ cursor) {
    __shared__ int lds[SCAN_T];
    int b = blockIdx.x, t = threadIdx.x;
    int base = b * SCAN_CHUNK + t * SCAN_ITEMS;
    int v[SCAN_ITEMS];
    int s = 0;
    #pragma unroll
    for (int i = 0; i < SCAN_ITEMS; ++i) {
        int idx = base + i;
        int d = (idx < N_NODES) ? deg[idx] : 0;
        v[i] = s;                 // exclusive prefix within thread
        s += d;
    }
    lds[t] = s;
    __syncthreads();
    // Hillis-Steele inclusive scan over the 256 thread sums
    for (int off = 1; off < SCAN_T; off <<= 1) {
        int x = lds[t];
        int y = (t >= off) ? lds[t - off] : 0;
        __syncthreads();
        lds[t] = x + y;
        __syncthreads();
    }
    int toff = ((t == 0) ? 0 : lds[t - 1]) + boff[b];
    #pragma unroll
    for (int i = 0; i < SCAN_ITEMS; ++i) {
        int idx = base + i;
        if (idx < N_NODES) {
            int val = v[i] + toff;
            row_ptr[idx] = val;
            cursor[idx]  = val;
        }
    }
    if (b == 0 && t == 0) row_ptr[N_NODES] = N_EDGES;
}

// ---------------------------------------------------------------------------
// CSR build step 3: scatter edges, packed (col, val-bits) as one uint2 store
// ---------------------------------------------------------------------------
__global__ void scatter_kernel(const int* __restrict__ rows,
                               const int* __restrict__ cols,
                               const float* __restrict__ vals,
                               int* __restrict__ cursor,
                               uint2* __restrict__ edges) {
    int e = blockIdx.x * blockDim.x + threadIdx.x;
    if (e < N_EDGES) {
        int r = rows[e];
        int p = atomicAdd(&cursor[r], 1);
        edges[p] = make_uint2((unsigned)cols[e], __float_as_uint(vals[e]));
    }
}

// ---------------------------------------------------------------------------
// CSR SpMM: one wave per row; lane d owns dim d. 4-deep unrolled gathers.
// ---------------------------------------------------------------------------
__global__ void __launch_bounds__(256)
spmm_csr_kernel(const int* __restrict__ row_ptr,
                const uint2* __restrict__ edges,
                const float* __restrict__ hin,
                float* __restrict__ hout) {
    int wave = (blockIdx.x * blockDim.x + threadIdx.x) >> 6;
    int lane = threadIdx.x & 63;
    if (wave >= N_NODES) return;
    int start = row_ptr[wave];
    int end   = row_ptr[wave + 1];
    float a0 = 0.f, a1 = 0.f, a2 = 0.f, a3 = 0.f;
    int e = start;
    for (; e + 4 <= end; e += 4) {
        uint2 e0 = edges[e], e1 = edges[e + 1], e2 = edges[e + 2], e3 = edges[e + 3];
        a0 += __uint_as_float(e0.y) * hin[(int)e0.x * DIM + lane];
        a1 += __uint_as_float(e1.y) * hin[(int)e1.x * DIM + lane];
        a2 += __uint_as_float(e2.y) * hin[(int)e2.x * DIM + lane];
        a3 += __uint_as_float(e3.y) * hin[(int)e3.x * DIM + lane];
    }
    for (; e < end; ++e) {
        uint2 ed = edges[e];
        a0 += __uint_as_float(ed.y) * hin[(int)ed.x * DIM + lane];
    }
    hout[wave * DIM + lane] = (a0 + a1) + (a2 + a3);
}

// ---------------------------------------------------------------------------
// CSR SpMM (last layer) fused with h_sum = ego + h1 + h2 + h3
// ---------------------------------------------------------------------------
__global__ void __launch_bounds__(256)
spmm_csr_fused_kernel(const int* __restrict__ row_ptr,
                      const uint2* __restrict__ edges,
                      const float* __restrict__ h2,      // gather source
                      const float* __restrict__ ego,
                      const float* __restrict__ h1,
                      float* __restrict__ h3,
                      float* __restrict__ hsum) {
    int wave = (blockIdx.x * blockDim.x + threadIdx.x) >> 6;
    int lane = threadIdx.x & 63;
    if (wave >= N_NODES) return;
    int start = row_ptr[wave];
    int end   = row_ptr[wave + 1];
    float a0 = 0.f, a1 = 0.f, a2 = 0.f, a3 = 0.f;
    int e = start;
    for (; e + 4 <= end; e += 4) {
        uint2 e0 = edges[e], e1 = edges[e + 1], e2 = edges[e + 2], e3 = edges[e + 3];
        a0 += __uint_as_float(e0.y) * h2[(int)e0.x * DIM + lane];
        a1 += __uint_as_float(e1.y) * h2[(int)e1.x * DIM + lane];
        a2 += __uint_as_float(e2.y) * h2[(int)e2.x * DIM + lane];
        a3 += __uint_as_float(e3.y) * h2[(int)e3.x * DIM + lane];
    }
    for (; e < end; ++e) {
        uint2 ed = edges[e];
        a0 += __uint_as_float(ed.y) * h2[(int)ed.x * DIM + lane];
    }
    float acc = (a0 + a1) + (a2 + a3);
    int o = wave * DIM + lane;
    h3[o]   = acc;
    hsum[o] = ego[o] + h1[o] + h2[o] + acc;
}

// ---------------------------------------------------------------------------
// Fallback SpMM via fp32 atomics (used only if ws_size too small for CSR)
// ---------------------------------------------------------------------------
__global__ void spmm_atomic_kernel(const int* __restrict__ rows,
                                   const int* __restrict__ cols,
                                   const float* __restrict__ vals,
                                   const float* __restrict__ hin,
                                   float* __restrict__ hout) {
    int e = blockIdx.x * 4 + (threadIdx.x >> 6);
    int d = threadIdx.x & 63;
    if (e < N_EDGES) {
        atomicAdd(&hout[rows[e] * DIM + d], vals[e] * hin[cols[e] * DIM + d]);
    }
}

__global__ void sum_kernel(const float4* __restrict__ a,
                           const float4* __restrict__ b,
                           const float4* __restrict__ c,
                           const float4* __restrict__ d,
                           float4* __restrict__ out) {
    int i = blockIdx.x * blockDim.x + threadIdx.x;
    if (i < (int)(NF / 4)) {
        float4 x = a[i], y = b[i], z = c[i], w = d[i];
        out[i] = make_float4(x.x + y.x + z.x + w.x,
                             x.y + y.y + z.y + w.y,
                             x.z + y.z + z.z + w.z,
                             x.w + y.w + z.w + w.w);
    }
}

extern "C" void kernel_launch(void* const* d_in, const int* in_sizes, int n_in,
                              void* d_out, int out_size, void* d_ws, size_t ws_size,
                              hipStream_t stream) {
    const float* user = (const float*)d_in[0];
    const float* item = (const float*)d_in[1];
    const float* vals = (const float*)d_in[2];
    const int*   rows = (const int*)d_in[3];
    const int*   cols = (const int*)d_in[4];

    float* out  = (float*)d_out;
    float* hsum = out;
    float* ego  = out + NF;
    float* h1   = out + 2 * NF;
    float* h2   = out + 3 * NF;
    float* h3   = out + 4 * NF;

    const int totF4 = (int)(NF / 4);

    concat_kernel<<<(totF4 + 255) / 256, 256, 0, stream>>>(
        (const float4*)user, (const float4*)item, (float4*)ego);

    // workspace layout: edges first (8B aligned), then int arrays
    const size_t nInt = (size_t)(N_NODES + 2);
    size_t need = (size_t)N_EDGES * 8 + (3 * nInt + 2 * 128) * 4;   // ~40.2 MB

    if (ws_size >= need) {
        uint2* edges   = (uint2*)d_ws;
        int*   deg     = (int*)(edges + N_EDGES);
        int*   row_ptr = deg + nInt;
        int*   cursor  = row_ptr + nInt;
        int*   bsum    = cursor + nInt;
        int*   boff    = bsum + 128;

        hipMemsetAsync(deg, 0, (size_t)N_NODES * sizeof(int), stream);
        hist_kernel<<<(N_EDGES + 255) / 256, 256, 0, stream>>>(rows, deg);
        scan_a_kernel<<<SCAN_NBLK, SCAN_T, 0, stream>>>(deg, bsum);
        scan_b_kernel<<<1, 128, 0, stream>>>(bsum, boff);
        scan_c_kernel<<<SCAN_NBLK, SCAN_T, 0, stream>>>(deg, boff, row_ptr, cursor);
        scatter_kernel<<<(N_EDGES + 255) / 256, 256, 0, stream>>>(
            rows, cols, vals, cursor, edges);

        const int spmmBlocks = (N_NODES * 64 + 255) / 256;  // 1 wave per row
        spmm_csr_kernel<<<spmmBlocks, 256, 0, stream>>>(row_ptr, edges, ego, h1);
        spmm_csr_kernel<<<spmmBlocks, 256, 0, stream>>>(row_ptr, edges, h1,  h2);
        spmm_csr_fused_kernel<<<spmmBlocks, 256, 0, stream>>>(
            row_ptr, edges, h2, ego, h1, h3, hsum);
    } else {
        hipMemsetAsync(h1, 0, (size_t)(3 * NF) * sizeof(float), stream);
        const int ablocks = (N_EDGES + 3) / 4;
        spmm_atomic_kernel<<<ablocks, 256, 0, stream>>>(rows, cols, vals, ego, h1);
        spmm_atomic_kernel<<<ablocks, 256, 0, stream>>>(rows, cols, vals, h1,  h2);
        spmm_atomic_kernel<<<ablocks, 256, 0, stream>>>(rows, cols, vals, h2,  h3);
        sum_kernel<<<(totF4 + 255) / 256, 256, 0, stream>>>(
            (const float4*)ego, (const float4*)h1, (const float4*)h2, (const float4*)h3,
            (float4*)hsum);
    }
}